// Round 4
// baseline (326.685 us; speedup 1.0000x reference)
//
#include <hip/hip_runtime.h>

// LightshiftaddLayer — inputs fp32: x (T,B,C), shift_W (C,C), shift_b (C),
// weight (8,7); output fp32 (T,B,C).
// R4: cast_x fused into GEMM staging (fp32 -> bf16 in-register before
// ds_write); removes a full 201 MB cast pass. Everything else unchanged.
constexpr int T_DIM = 4096;
constexpr int B_DIM = 16;
constexpr int C_DIM = 512;
constexpr int K_CONV = 7;
constexpr int M_DIM = T_DIM * B_DIM;   // 65536 GEMM rows
constexpr int BC = B_DIM * C_DIM;      // 8192

typedef __attribute__((ext_vector_type(8))) short bf16x8;
typedef __attribute__((ext_vector_type(4))) float f32x4;
typedef __attribute__((ext_vector_type(8))) float f32x8;
typedef __attribute__((ext_vector_type(4))) unsigned int u32x4;

__device__ __forceinline__ unsigned short f2bf(float f) {
  unsigned u = __float_as_uint(f);
  u += 0x7fffu + ((u >> 16) & 1u);   // RNE
  return (unsigned short)(u >> 16);
}
__device__ __forceinline__ unsigned pack2(float a, float b) {
  return (unsigned)f2bf(a) | (((unsigned)f2bf(b)) << 16);
}
__device__ __forceinline__ u32x4 pack8(f32x4 lo, f32x4 hi) {
  u32x4 o;
  o[0] = pack2(lo[0], lo[1]);
  o[1] = pack2(lo[2], lo[3]);
  o[2] = pack2(hi[0], hi[1]);
  o[3] = pack2(hi[2], hi[3]);
  return o;
}

// ---------------------------------------------------------------- quantize W -> bf16
__global__ __launch_bounds__(256) void quantize_w(
    const float* __restrict__ W, unsigned short* __restrict__ Wq) {
  int i = blockIdx.x * 256 + threadIdx.x;
  float w = W[i];
  float a = fabsf(w) + 1e-12f;
  float q = exp2f(rintf(log2f(a)));       // rintf = RNE, matches jnp.round
  q = (w > 0.f) ? q : ((w < 0.f) ? -q : 0.f);
  Wq[i] = f2bf(q);                        // powers of two: exact in bf16
}

// ---------------------------------------------------------------- GEMM (B^T)
// Y[m,n] = sum_k X[m,k]*Bt[n,k] + bias[n]; X fp32 (65536,512) cast in-flight,
// Bt bf16 (512,512). Y bf16.
constexpr int BK = 32;

__global__ __launch_bounds__(256, 2) void gemm_bt(
    const float* __restrict__ X, const short* __restrict__ Bt,
    const float* __restrict__ bias, unsigned short* __restrict__ Y) {
  constexpr int K = C_DIM, N = C_DIM;
  __shared__ __align__(16) short As[128 * BK];   // 8 KB
  __shared__ __align__(16) short Bs[128 * BK];   // 8 KB

  const int t    = threadIdx.x;
  const int lane = t & 63;
  const int wid  = t >> 6;               // 4 waves: 2x2 of 64x64
  const int m0 = blockIdx.y * 128;
  const int n0 = blockIdx.x * 128;

  // staging: 4 threads per row-of-32-k (8 elements each)
  const int sr = t >> 2;                 // 0..63
  const int sc = (t & 3) * 8;
  const float* pX0 = X + (long)(m0 + sr) * K + sc;
  const float* pX1 = X + (long)(m0 + 64 + sr) * K + sc;
  const short* pB0 = Bt + (long)(n0 + sr) * K + sc;
  const short* pB1 = Bt + (long)(n0 + 64 + sr) * K + sc;

  // fragment indices (A frag: A[m=lane&15][k=(lane>>4)*8+j])
  const int fr = lane & 15;
  const int fq = lane >> 4;
  const int wm = (wid >> 1) * 64;
  const int wn = (wid & 1) * 64;

  f32x4 acc[4][4] = {};

  for (int k0 = 0; k0 < K; k0 += BK) {
    f32x4 xa0 = *(const f32x4*)(pX0 + k0);
    f32x4 xa1 = *(const f32x4*)(pX0 + k0 + 4);
    f32x4 xb0 = *(const f32x4*)(pX1 + k0);
    f32x4 xb1 = *(const f32x4*)(pX1 + k0 + 4);
    bf16x8 b0 = *(const bf16x8*)(pB0 + k0);
    bf16x8 b1 = *(const bf16x8*)(pB1 + k0);
    u32x4 a0 = pack8(xa0, xa1);            // fp32 -> bf16, RNE (matches cast_x)
    u32x4 a1 = pack8(xb0, xb1);
    __syncthreads();                       // prev iter's LDS reads done
    *(u32x4*)&As[sr * BK + sc]         = a0;
    *(u32x4*)&As[(64 + sr) * BK + sc]  = a1;
    *(bf16x8*)&Bs[sr * BK + sc]        = b0;
    *(bf16x8*)&Bs[(64 + sr) * BK + sc] = b1;
    __syncthreads();                       // staging visible

    bf16x8 af[4], bfr[4];
#pragma unroll
    for (int i = 0; i < 4; ++i)
      af[i] = *(const bf16x8*)&As[(wm + i * 16 + fr) * BK + fq * 8];
#pragma unroll
    for (int j = 0; j < 4; ++j)
      bfr[j] = *(const bf16x8*)&Bs[(wn + j * 16 + fr) * BK + fq * 8];
#pragma unroll
    for (int i = 0; i < 4; ++i)
#pragma unroll
      for (int j = 0; j < 4; ++j)
        acc[i][j] = __builtin_amdgcn_mfma_f32_16x16x32_bf16(af[i], bfr[j], acc[i][j], 0, 0, 0);
  }

  // epilogue: C/D layout col=lane&15, row=(lane>>4)*4+reg
#pragma unroll
  for (int j = 0; j < 4; ++j) {
    const int gn = n0 + wn + j * 16 + fr;
    const float bv = bias[gn];
#pragma unroll
    for (int i = 0; i < 4; ++i) {
#pragma unroll
      for (int r = 0; r < 4; ++r) {
        const int gm = m0 + wm + i * 16 + fq * 4 + r;
        Y[(long)gm * N + gn] = f2bf(acc[i][j][r] + bv);
      }
    }
  }
}

// ---------------------------------------------------------------- depthwise conv
// out[t,b,c] = sum_k y[t+k-3,b,c] * softmax(weight[h])[k], h = c>>6.
constexpr int CHT = 16;   // t's per thread

__device__ __forceinline__ u32x4 loadY(const unsigned short* Y, int t, long off) {
  if ((unsigned)t < (unsigned)T_DIM)
    return *(const u32x4*)(Y + (long)t * BC + off);
  u32x4 z = {0u, 0u, 0u, 0u};
  return z;
}

__device__ __forceinline__ f32x8 unpack8(u32x4 u) {
  f32x8 r;
#pragma unroll
  for (int i = 0; i < 4; ++i) {
    unsigned w = u[i];
    r[2 * i]     = __uint_as_float(w << 16);
    r[2 * i + 1] = __uint_as_float(w & 0xffff0000u);
  }
  return r;
}

__global__ __launch_bounds__(256) void lconv(
    const unsigned short* __restrict__ Y, const float* __restrict__ W,
    float* __restrict__ O) {
  const int tid  = blockIdx.x * 256 + threadIdx.x;
  const int cvec = tid & 63;               // 8-channel vector index
  const int b    = (tid >> 6) & 15;
  const int tc   = tid >> 10;              // t chunk
  const int t0   = tc * CHT;
  const long off = (long)b * C_DIM + cvec * 8;
  const int h    = cvec >> 3;              // head = c/64

  // softmax over the head's 7 taps (fp32, matches ref)
  float wf[K_CONV];
  float mx = -1e30f;
#pragma unroll
  for (int k = 0; k < K_CONV; ++k) { wf[k] = W[h * K_CONV + k]; mx = fmaxf(mx, wf[k]); }
  float s = 0.f;
#pragma unroll
  for (int k = 0; k < K_CONV; ++k) { wf[k] = __expf(wf[k] - mx); s += wf[k]; }
  const float inv = 1.f / s;
#pragma unroll
  for (int k = 0; k < K_CONV; ++k) wf[k] *= inv;

  f32x8 win[K_CONV];
#pragma unroll
  for (int i = 0; i < 6; ++i) win[i] = unpack8(loadY(Y, t0 - 3 + i, off));

#pragma unroll
  for (int j = 0; j < CHT; ++j) {
    win[6] = unpack8(loadY(Y, t0 + 3 + j, off));
    f32x8 acc = win[0] * wf[0];
#pragma unroll
    for (int k = 1; k < K_CONV; ++k) acc += win[k] * wf[k];
    float* op = O + (long)(t0 + j) * BC + off;
    *(f32x4*)op       = f32x4{acc[0], acc[1], acc[2], acc[3]};
    *(f32x4*)(op + 4) = f32x4{acc[4], acc[5], acc[6], acc[7]};
#pragma unroll
    for (int k = 0; k < 6; ++k) win[k] = win[k + 1];
  }
}

// ---------------------------------------------------------------- launch
extern "C" void kernel_launch(void* const* d_in, const int* in_sizes, int n_in,
                              void* d_out, int out_size, void* d_ws, size_t ws_size,
                              hipStream_t stream) {
  const float* x       = (const float*)d_in[0];  // (T,B,C) fp32
  const float* shift_W = (const float*)d_in[1];  // (C,C) fp32
  const float* shift_b = (const float*)d_in[2];  // (C) fp32
  const float* weight  = (const float*)d_in[3];  // (8,7) fp32
  float* out = (float*)d_out;

  unsigned short* Wq = (unsigned short*)d_ws;        // 512 KB bf16 Wq
  unsigned short* Y  = Wq + C_DIM * C_DIM;           // 67 MB bf16 y

  quantize_w<<<(C_DIM * C_DIM) / 256, 256, 0, stream>>>(shift_W, Wq);
  gemm_bt<<<dim3(C_DIM / 128, M_DIM / 128), 256, 0, stream>>>(
      x, (const short*)Wq, shift_b, Y);
  lconv<<<(M_DIM / CHT) * (C_DIM / 8) / 256, 256, 0, stream>>>(Y, weight, out);
}

// Round 5
// 320.708 us; speedup vs baseline: 1.0186x; 1.0186x over previous
//
#include <hip/hip_runtime.h>

// LightshiftaddLayer — inputs fp32: x (T,B,C), shift_W (C,C), shift_b (C),
// weight (8,7); output fp32 (T,B,C).
// R5: gemm_bt gets (1) XCD-aware block swizzle so the 4 n-blocks sharing an
// X m-tile run on one XCD (FETCH 263->~160MB), (2) LDS row stride 40 elems
// to kill 8-way bank conflicts, (3) register prefetch pipeline to hide
// global-load latency behind MFMA. lconv: CHT 16->32.
constexpr int T_DIM = 4096;
constexpr int B_DIM = 16;
constexpr int C_DIM = 512;
constexpr int K_CONV = 7;
constexpr int M_DIM = T_DIM * B_DIM;   // 65536 GEMM rows
constexpr int BC = B_DIM * C_DIM;      // 8192

typedef __attribute__((ext_vector_type(8))) short bf16x8;
typedef __attribute__((ext_vector_type(4))) float f32x4;
typedef __attribute__((ext_vector_type(8))) float f32x8;
typedef __attribute__((ext_vector_type(4))) unsigned int u32x4;

__device__ __forceinline__ unsigned short f2bf(float f) {
  unsigned u = __float_as_uint(f);
  u += 0x7fffu + ((u >> 16) & 1u);   // RNE
  return (unsigned short)(u >> 16);
}
__device__ __forceinline__ unsigned pack2(float a, float b) {
  return (unsigned)f2bf(a) | (((unsigned)f2bf(b)) << 16);
}
__device__ __forceinline__ u32x4 pack8(f32x4 lo, f32x4 hi) {
  u32x4 o;
  o[0] = pack2(lo[0], lo[1]);
  o[1] = pack2(lo[2], lo[3]);
  o[2] = pack2(hi[0], hi[1]);
  o[3] = pack2(hi[2], hi[3]);
  return o;
}

// ---------------------------------------------------------------- quantize W -> bf16
__global__ __launch_bounds__(256) void quantize_w(
    const float* __restrict__ W, unsigned short* __restrict__ Wq) {
  int i = blockIdx.x * 256 + threadIdx.x;
  float w = W[i];
  float a = fabsf(w) + 1e-12f;
  float q = exp2f(rintf(log2f(a)));       // rintf = RNE, matches jnp.round
  q = (w > 0.f) ? q : ((w < 0.f) ? -q : 0.f);
  Wq[i] = f2bf(q);                        // powers of two: exact in bf16
}

// ---------------------------------------------------------------- GEMM (B^T)
// Y[m,n] = sum_k X[m,k]*Bt[n,k] + bias[n]; X fp32 cast in-flight, Bt bf16.
constexpr int BK = 32;
constexpr int LDS_STRIDE = 40;   // 32 + 8 pad elems: fragment reads 2-way max

__global__ __launch_bounds__(256, 2) void gemm_bt(
    const float* __restrict__ X, const short* __restrict__ Bt,
    const float* __restrict__ bias, unsigned short* __restrict__ Y) {
  constexpr int K = C_DIM, N = C_DIM;
  __shared__ __align__(16) short As[128 * LDS_STRIDE];   // 10 KB
  __shared__ __align__(16) short Bs[128 * LDS_STRIDE];   // 10 KB

  // XCD swizzle: ids 8 apart share an X m-tile and land on one XCD
  // (dispatch round-robins linear id % 8 across XCDs).
  const int id   = blockIdx.x;            // 0..2047
  const int xcd  = id & 7;
  const int slot = id >> 3;               // 0..255
  const int nb   = slot & 3;
  const int mb   = xcd * 64 + (slot >> 2);
  const int m0 = mb * 128;
  const int n0 = nb * 128;

  const int t    = threadIdx.x;
  const int lane = t & 63;
  const int wid  = t >> 6;               // 4 waves: 2x2 of 64x64

  // staging: 4 threads per row-of-32-k (8 elements each)
  const int sr = t >> 2;                 // 0..63
  const int sc = (t & 3) * 8;
  const float* pX0 = X + (long)(m0 + sr) * K + sc;
  const float* pX1 = X + (long)(m0 + 64 + sr) * K + sc;
  const short* pB0 = Bt + (long)(n0 + sr) * K + sc;
  const short* pB1 = Bt + (long)(n0 + 64 + sr) * K + sc;

  // fragment indices (A frag: A[m=lane&15][k=(lane>>4)*8+j])
  const int fr = lane & 15;
  const int fq = lane >> 4;
  const int wm = (wid >> 1) * 64;
  const int wn = (wid & 1) * 64;

  f32x4 acc[4][4] = {};

  // prologue loads (k0 = 0)
  f32x4 xa0 = *(const f32x4*)(pX0);
  f32x4 xa1 = *(const f32x4*)(pX0 + 4);
  f32x4 xb0 = *(const f32x4*)(pX1);
  f32x4 xb1 = *(const f32x4*)(pX1 + 4);
  bf16x8 b0 = *(const bf16x8*)(pB0);
  bf16x8 b1 = *(const bf16x8*)(pB1);

  for (int k0 = 0; k0 < K; k0 += BK) {
    u32x4 a0 = pack8(xa0, xa1);            // fp32 -> bf16 RNE
    u32x4 a1 = pack8(xb0, xb1);
    bf16x8 bs0 = b0, bs1 = b1;
    __syncthreads();                       // prev iter's LDS reads done
    *(u32x4*)&As[sr * LDS_STRIDE + sc]         = a0;
    *(u32x4*)&As[(64 + sr) * LDS_STRIDE + sc]  = a1;
    *(bf16x8*)&Bs[sr * LDS_STRIDE + sc]        = bs0;
    *(bf16x8*)&Bs[(64 + sr) * LDS_STRIDE + sc] = bs1;
    __syncthreads();                       // staging visible

    if (k0 + BK < K) {                     // prefetch next tile (wave-uniform)
      xa0 = *(const f32x4*)(pX0 + k0 + BK);
      xa1 = *(const f32x4*)(pX0 + k0 + BK + 4);
      xb0 = *(const f32x4*)(pX1 + k0 + BK);
      xb1 = *(const f32x4*)(pX1 + k0 + BK + 4);
      b0 = *(const bf16x8*)(pB0 + k0 + BK);
      b1 = *(const bf16x8*)(pB1 + k0 + BK);
    }

    bf16x8 af[4], bfr[4];
#pragma unroll
    for (int i = 0; i < 4; ++i)
      af[i] = *(const bf16x8*)&As[(wm + i * 16 + fr) * LDS_STRIDE + fq * 8];
#pragma unroll
    for (int j = 0; j < 4; ++j)
      bfr[j] = *(const bf16x8*)&Bs[(wn + j * 16 + fr) * LDS_STRIDE + fq * 8];
#pragma unroll
    for (int i = 0; i < 4; ++i)
#pragma unroll
      for (int j = 0; j < 4; ++j)
        acc[i][j] = __builtin_amdgcn_mfma_f32_16x16x32_bf16(af[i], bfr[j], acc[i][j], 0, 0, 0);
  }

  // epilogue: C/D layout col=lane&15, row=(lane>>4)*4+reg
#pragma unroll
  for (int j = 0; j < 4; ++j) {
    const int gn = n0 + wn + j * 16 + fr;
    const float bv = bias[gn];
#pragma unroll
    for (int i = 0; i < 4; ++i) {
#pragma unroll
      for (int r = 0; r < 4; ++r) {
        const int gm = m0 + wm + i * 16 + fq * 4 + r;
        Y[(long)gm * N + gn] = f2bf(acc[i][j][r] + bv);
      }
    }
  }
}

// ---------------------------------------------------------------- depthwise conv
// out[t,b,c] = sum_k y[t+k-3,b,c] * softmax(weight[h])[k], h = c>>6.
constexpr int CHT = 32;   // t's per thread

__device__ __forceinline__ u32x4 loadY(const unsigned short* Y, int t, long off) {
  if ((unsigned)t < (unsigned)T_DIM)
    return *(const u32x4*)(Y + (long)t * BC + off);
  u32x4 z = {0u, 0u, 0u, 0u};
  return z;
}

__device__ __forceinline__ f32x8 unpack8(u32x4 u) {
  f32x8 r;
#pragma unroll
  for (int i = 0; i < 4; ++i) {
    unsigned w = u[i];
    r[2 * i]     = __uint_as_float(w << 16);
    r[2 * i + 1] = __uint_as_float(w & 0xffff0000u);
  }
  return r;
}

__global__ __launch_bounds__(256) void lconv(
    const unsigned short* __restrict__ Y, const float* __restrict__ W,
    float* __restrict__ O) {
  const int tid  = blockIdx.x * 256 + threadIdx.x;
  const int cvec = tid & 63;               // 8-channel vector index
  const int b    = (tid >> 6) & 15;
  const int tc   = tid >> 10;              // t chunk
  const int t0   = tc * CHT;
  const long off = (long)b * C_DIM + cvec * 8;
  const int h    = cvec >> 3;              // head = c/64

  // softmax over the head's 7 taps (fp32, matches ref)
  float wf[K_CONV];
  float mx = -1e30f;
#pragma unroll
  for (int k = 0; k < K_CONV; ++k) { wf[k] = W[h * K_CONV + k]; mx = fmaxf(mx, wf[k]); }
  float s = 0.f;
#pragma unroll
  for (int k = 0; k < K_CONV; ++k) { wf[k] = __expf(wf[k] - mx); s += wf[k]; }
  const float inv = 1.f / s;
#pragma unroll
  for (int k = 0; k < K_CONV; ++k) wf[k] *= inv;

  f32x8 win[K_CONV];
#pragma unroll
  for (int i = 0; i < 6; ++i) win[i] = unpack8(loadY(Y, t0 - 3 + i, off));

#pragma unroll
  for (int j = 0; j < CHT; ++j) {
    win[6] = unpack8(loadY(Y, t0 + 3 + j, off));
    f32x8 acc = win[0] * wf[0];
#pragma unroll
    for (int k = 1; k < K_CONV; ++k) acc += win[k] * wf[k];
    float* op = O + (long)(t0 + j) * BC + off;
    *(f32x4*)op       = f32x4{acc[0], acc[1], acc[2], acc[3]};
    *(f32x4*)(op + 4) = f32x4{acc[4], acc[5], acc[6], acc[7]};
#pragma unroll
    for (int k = 0; k < 6; ++k) win[k] = win[k + 1];
  }
}

// ---------------------------------------------------------------- launch
extern "C" void kernel_launch(void* const* d_in, const int* in_sizes, int n_in,
                              void* d_out, int out_size, void* d_ws, size_t ws_size,
                              hipStream_t stream) {
  const float* x       = (const float*)d_in[0];  // (T,B,C) fp32
  const float* shift_W = (const float*)d_in[1];  // (C,C) fp32
  const float* shift_b = (const float*)d_in[2];  // (C) fp32
  const float* weight  = (const float*)d_in[3];  // (8,7) fp32
  float* out = (float*)d_out;

  unsigned short* Wq = (unsigned short*)d_ws;        // 512 KB bf16 Wq
  unsigned short* Y  = Wq + C_DIM * C_DIM;           // 67 MB bf16 y

  quantize_w<<<(C_DIM * C_DIM) / 256, 256, 0, stream>>>(shift_W, Wq);
  gemm_bt<<<(M_DIM / 128) * (C_DIM / 128), 256, 0, stream>>>(
      x, (const short*)Wq, shift_b, Y);
  lconv<<<(M_DIM / CHT) * (C_DIM / 8) / 256, 256, 0, stream>>>(Y, weight, out);
}